// Round 14
// baseline (406.034 us; speedup 1.0000x reference)
//
#include <hip/hip_runtime.h>
#include <math.h>

#define T_LEN 2048
#define HIDN  2048
#define HKN   16
#define DKN   96
#define HVN   16
#define DVN   192
#define KDIMN 1536
#define VDIMN 3072
#define QKVD  6144
#define CHUNKN 64
#define NCHUNK 32
#define EPSF 1e-6f
#define TN_STRIDE 10240
#define WQG_ST 6656
#define AT_ST  4608
#define CT_ST  18432
#define S_ST   19968
#define U_ST   12288

typedef __attribute__((ext_vector_type(8))) short short8;
typedef __attribute__((ext_vector_type(4))) float f32x4;

__device__ __forceinline__ unsigned short f2bf(float f) {
    unsigned int u = __float_as_uint(f);
    unsigned int r = (u + 0x7FFFu + ((u >> 16) & 1u)) >> 16;
    return (unsigned short)r;
}
__device__ __forceinline__ float bf2f(unsigned short u) {
    return __uint_as_float(((unsigned int)u) << 16);
}
__device__ __forceinline__ float siluf(float x) { return x / (1.f + expf(-x)); }

__device__ __forceinline__ void gld_lds16(const void* g, void* l) {
    __builtin_amdgcn_global_load_lds((const __attribute__((address_space(1))) unsigned int*)g,
                                     (__attribute__((address_space(3))) unsigned int*)l, 16, 0, 0);
}

// stage a 128x64 bf16 tile (row-major, swizzled) via global_load_lds.
// LDS dest linear; global SOURCE pre-permuted so that a swizzled ds_read
// (byte ^= ((row&7)<<4)) returns logical (row, col).
__device__ __forceinline__ void stage_tile64(const unsigned short* __restrict__ G,
                                             size_t row0, int K, int kt,
                                             unsigned short* lds, int wave, int lane) {
#pragma unroll
    for (int q = 0; q < 4; ++q) {
        int c = q * 4 + wave;
        int row = c * 8 + (lane >> 3);
        int col = ((lane & 7) ^ (lane >> 3)) * 8;
        gld_lds16(G + (row0 + row) * (size_t)K + kt + col, (char*)lds + c * 1024);
    }
}
__device__ __forceinline__ short8 lds_read_swz(const unsigned short* lds, int row, int kbyte) {
    return *(const short8*)((const char*)lds + row * 128 + (kbyte ^ ((row & 7) << 4)));
}

// ---------------- merged prep: beta/g projection (+X cast) AND weight transposes ----------------
__global__ __launch_bounds__(256) void prep_all(
    const float* __restrict__ X,
    const float* __restrict__ Wb, const float* __restrict__ Wa,
    const float* __restrict__ A_log, const float* __restrict__ dtb,
    float* __restrict__ bvec, float* __restrict__ gvec, unsigned short* __restrict__ Xbf,
    const float* __restrict__ Wq, const float* __restrict__ Wk,
    const float* __restrict__ Wv, const float* __restrict__ Wg,
    const float* __restrict__ Wo,
    unsigned short* __restrict__ WallT, unsigned short* __restrict__ WoT) {
    __shared__ float tile[64][65];
    __shared__ float red[4][8][4];
    int bid = blockIdx.x;
    int tid = threadIdx.x;
    if (bid < 2048) {
        int t = bid;
        int cg = tid & 7, ks = tid >> 3;
        int wave = tid >> 6, lane = tid & 63;
        const float* xr = X + (size_t)t * HIDN;
        const float* Wsel = (cg < 4) ? Wb : Wa;
        int cc = (cg & 3) * 4;
        float ax = 0.f, ay = 0.f, az = 0.f, aw = 0.f;
#pragma unroll 4
        for (int i = 0; i < 16; ++i) {
            int k = (ks + 32 * i) * 4;
            float4 xv = *(const float4*)(xr + k);
            if (cg == 0) {
                ushort4 xo;
                xo.x = f2bf(xv.x); xo.y = f2bf(xv.y); xo.z = f2bf(xv.z); xo.w = f2bf(xv.w);
                *(ushort4*)(Xbf + (size_t)t * HIDN + k) = xo;
            }
            float4 w0 = *(const float4*)(Wsel + (size_t)(k + 0) * 16 + cc);
            float4 w1 = *(const float4*)(Wsel + (size_t)(k + 1) * 16 + cc);
            float4 w2 = *(const float4*)(Wsel + (size_t)(k + 2) * 16 + cc);
            float4 w3 = *(const float4*)(Wsel + (size_t)(k + 3) * 16 + cc);
            ax += xv.x * w0.x + xv.y * w1.x + xv.z * w2.x + xv.w * w3.x;
            ay += xv.x * w0.y + xv.y * w1.y + xv.z * w2.y + xv.w * w3.y;
            az += xv.x * w0.z + xv.y * w1.z + xv.z * w2.z + xv.w * w3.z;
            aw += xv.x * w0.w + xv.y * w1.w + xv.z * w2.w + xv.w * w3.w;
        }
#pragma unroll
        for (int off = 8; off <= 32; off <<= 1) {
            ax += __shfl_xor(ax, off, 64);
            ay += __shfl_xor(ay, off, 64);
            az += __shfl_xor(az, off, 64);
            aw += __shfl_xor(aw, off, 64);
        }
        if ((lane >> 3) == 0) {
            red[wave][cg][0] = ax; red[wave][cg][1] = ay;
            red[wave][cg][2] = az; red[wave][cg][3] = aw;
        }
        __syncthreads();
        if (tid < 8) {
            float tot[4];
#pragma unroll
            for (int j = 0; j < 4; ++j)
                tot[j] = red[0][tid][j] + red[1][tid][j] + red[2][tid][j] + red[3][tid][j];
            int c0 = (tid & 3) * 4;
            if (tid < 4) {
#pragma unroll
                for (int j = 0; j < 4; ++j)
                    bvec[(size_t)t * 16 + c0 + j] = 2.f / (1.f + expf(-tot[j]));
            } else {
#pragma unroll
                for (int j = 0; j < 4; ++j) {
                    float a = tot[j] + dtb[c0 + j];
                    float sp = (a > 20.f) ? a : log1pf(expf(a));
                    gvec[(size_t)t * 16 + c0 + j] = -expf(A_log[c0 + j]) * sp;
                }
            }
        }
    } else {
        int b2 = bid - 2048;
        const float* W; unsigned short* Wt; int K, N, l;
        if (b2 < 768)       { W = Wq; Wt = WallT;                       K = 2048; N = 1536; l = b2; }
        else if (b2 < 1536) { W = Wk; Wt = WallT + (size_t)1536 * 2048; K = 2048; N = 1536; l = b2 - 768; }
        else if (b2 < 3072) { W = Wv; Wt = WallT + (size_t)3072 * 2048; K = 2048; N = 3072; l = b2 - 1536; }
        else if (b2 < 4608) { W = Wg; Wt = WallT + (size_t)6144 * 2048; K = 2048; N = 3072; l = b2 - 3072; }
        else                { W = Wo; Wt = WoT;                         K = 3072; N = 2048; l = b2 - 4608; }
        int nbx = N >> 6;
        int n0 = (l % nbx) * 64, k0 = (l / nbx) * 64;
        int tx = tid & 63, ty = tid >> 6;
        for (int r = ty; r < 64; r += 4) tile[r][tx] = W[(size_t)(k0 + r) * N + n0 + tx];
        __syncthreads();
        for (int r = ty; r < 64; r += 4) Wt[(size_t)(n0 + r) * K + k0 + tx] = f2bf(tile[tx][r]);
    }
}

// ---------------- fused projection GEMM, 2-phase dbuf, BK=64 swizzled ----------------
__global__ __launch_bounds__(256) void gemm_bt2(const unsigned short* __restrict__ A,
                                                const unsigned short* __restrict__ Bt,
                                                float* __restrict__ C1, int ld1, int nblk1,
                                                unsigned short* __restrict__ C2, int ld2,
                                                int M, int K) {
    __shared__ __align__(16) unsigned short As[2][128 * 64];
    __shared__ __align__(16) unsigned short Bs[2][128 * 64];
    int tid = threadIdx.x;
    int wave = tid >> 6, lane = tid & 63;
    int bm = blockIdx.y, bn = blockIdx.x;
    f32x4 acc[4][4] = {};
    int wr = wave >> 1, wc = wave & 1;
    const size_t a_row0 = (size_t)bm * 128;
    const size_t b_row0 = (size_t)bn * 128;
    int row_a[4], row_b[4];
#pragma unroll
    for (int i = 0; i < 4; ++i) {
        row_a[i] = wr * 64 + i * 16 + (lane & 15);
        row_b[i] = wc * 64 + i * 16 + (lane & 15);
    }
    int niter = K >> 6;
    stage_tile64(A, a_row0, K, 0, &As[0][0], wave, lane);
    stage_tile64(Bt, b_row0, K, 0, &Bs[0][0], wave, lane);
    __syncthreads();
    for (int i = 0; i < niter; ++i) {
        int cur = i & 1;
        if (i + 1 < niter) {
            stage_tile64(A, a_row0, K, (i + 1) * 64, &As[cur ^ 1][0], wave, lane);
            stage_tile64(Bt, b_row0, K, (i + 1) * 64, &Bs[cur ^ 1][0], wave, lane);
        }
#pragma unroll
        for (int ks2 = 0; ks2 < 2; ++ks2) {
            int kb = ks2 * 64 + (lane >> 4) * 16;
            short8 af[4], bfr[4];
#pragma unroll
            for (int mi = 0; mi < 4; ++mi) af[mi] = lds_read_swz(&As[cur][0], row_a[mi], kb);
#pragma unroll
            for (int ni = 0; ni < 4; ++ni) bfr[ni] = lds_read_swz(&Bs[cur][0], row_b[ni], kb);
#pragma unroll
            for (int mi = 0; mi < 4; ++mi)
#pragma unroll
                for (int ni = 0; ni < 4; ++ni)
                    acc[mi][ni] = __builtin_amdgcn_mfma_f32_16x16x32_bf16(af[mi], bfr[ni], acc[mi][ni], 0, 0, 0);
        }
        __syncthreads();
    }
    if (bn < nblk1) {
        int colb = bn * 128;
#pragma unroll
        for (int mi = 0; mi < 4; ++mi) {
            int rbase = bm * 128 + wr * 64 + mi * 16 + (lane >> 4) * 4;
#pragma unroll
            for (int ni = 0; ni < 4; ++ni) {
                int col = colb + wc * 64 + ni * 16 + (lane & 15);
#pragma unroll
                for (int j = 0; j < 4; ++j)
                    C1[(size_t)(rbase + j) * ld1 + col] = acc[mi][ni][j];
            }
        }
    } else {
        int colb = (bn - nblk1) * 128;
#pragma unroll
        for (int mi = 0; mi < 4; ++mi) {
            int rbase = bm * 128 + wr * 64 + mi * 16 + (lane >> 4) * 4;
#pragma unroll
            for (int ni = 0; ni < 4; ++ni) {
                int col = colb + wc * 64 + ni * 16 + (lane & 15);
#pragma unroll
                for (int j = 0; j < 4; ++j)
                    C2[(size_t)(rbase + j) * ld2 + col] = f2bf(acc[mi][ni][j]);
            }
        }
    }
}

// ---------------- split-K GEMM (SPLIT=3), 2-phase dbuf, BK=64 swizzled ----------------
__global__ __launch_bounds__(256) void gemm_btk(const unsigned short* __restrict__ A,
                                                const unsigned short* __restrict__ Bt,
                                                float* __restrict__ C, float* __restrict__ Cp,
                                                int M, int N, int K) {
    __shared__ __align__(16) unsigned short As[2][128 * 64];
    __shared__ __align__(16) unsigned short Bs[2][128 * 64];
    int tid = threadIdx.x;
    int wave = tid >> 6, lane = tid & 63;
    int bm = blockIdx.y, bn = blockIdx.x, kz = blockIdx.z;
    int kchunk = K / 3;
    int kbeg = kz * kchunk;
    f32x4 acc[4][4] = {};
    int wr = wave >> 1, wc = wave & 1;
    const size_t a_row0 = (size_t)bm * 128;
    const size_t b_row0 = (size_t)bn * 128;
    int row_a[4], row_b[4];
#pragma unroll
    for (int i = 0; i < 4; ++i) {
        row_a[i] = wr * 64 + i * 16 + (lane & 15);
        row_b[i] = wc * 64 + i * 16 + (lane & 15);
    }
    int niter = kchunk >> 6;
    stage_tile64(A, a_row0, K, kbeg, &As[0][0], wave, lane);
    stage_tile64(Bt, b_row0, K, kbeg, &Bs[0][0], wave, lane);
    __syncthreads();
    for (int i = 0; i < niter; ++i) {
        int cur = i & 1;
        if (i + 1 < niter) {
            stage_tile64(A, a_row0, K, kbeg + (i + 1) * 64, &As[cur ^ 1][0], wave, lane);
            stage_tile64(Bt, b_row0, K, kbeg + (i + 1) * 64, &Bs[cur ^ 1][0], wave, lane);
        }
#pragma unroll
        for (int ks2 = 0; ks2 < 2; ++ks2) {
            int kb = ks2 * 64 + (lane >> 4) * 16;
            short8 af[4], bfr[4];
#pragma unroll
            for (int mi = 0; mi < 4; ++mi) af[mi] = lds_read_swz(&As[cur][0], row_a[mi], kb);
#pragma unroll
            for (int ni = 0; ni < 4; ++ni) bfr[ni] = lds_read_swz(&Bs[cur][0], row_b[ni], kb);
#pragma unroll
            for (int mi = 0; mi < 4; ++mi)
#pragma unroll
                for (int ni = 0; ni < 4; ++ni)
                    acc[mi][ni] = __builtin_amdgcn_mfma_f32_16x16x32_bf16(af[mi], bfr[ni], acc[mi][ni], 0, 0, 0);
        }
        __syncthreads();
    }
    float* Cout = (kz == 0) ? C : (Cp + (size_t)(kz - 1) * M * N);
#pragma unroll
    for (int mi = 0; mi < 4; ++mi) {
        int rbase = bm * 128 + wr * 64 + mi * 16 + (lane >> 4) * 4;
#pragma unroll
        for (int ni = 0; ni < 4; ++ni) {
            int col = bn * 128 + wc * 64 + ni * 16 + (lane & 15);
#pragma unroll
            for (int j = 0; j < 4; ++j)
                Cout[(size_t)(rbase + j) * N + col] = acc[mi][ni][j];
        }
    }
}

// ---------------- addk: out += p0 + p1 ----------------
__global__ void addk(float* __restrict__ out, const float* __restrict__ p, int n) {
    int i = (blockIdx.x * blockDim.x + threadIdx.x) * 4;
    if (i >= n) return;
    float4 a = *(const float4*)(out + i);
    float4 b = *(const float4*)(p + i);
    float4 c = *(const float4*)(p + n + i);
    a.x += b.x + c.x; a.y += b.y + c.y; a.z += b.z + c.z; a.w += b.w + c.w;
    *(float4*)(out + i) = a;
}

// ---------------- phase 1 (MFMA): fused conv+SiLU + WY-prep + tprep ----------------
// doubling commuted: P_{k+1} = P_k + P_k@A_k (6 levels, D and E in one phase, 12 barriers)
__global__ __launch_bounds__(256) void phase1_mfma(
    const float* __restrict__ Cqkv,
    const float* __restrict__ cq, const float* __restrict__ ck, const float* __restrict__ cv,
    const float* __restrict__ gvec, const float* __restrict__ bvec,
    float* __restrict__ u_ws, unsigned short* __restrict__ w_bf,
    unsigned short* __restrict__ qg_bf, unsigned short* __restrict__ at_bf,
    unsigned short* __restrict__ Ct, unsigned short* __restrict__ Tn) {
    int n = blockIdx.x, h = blockIdx.y;
    int t0 = n * CHUNKN;
    int tid = threadIdx.x;
    int wave = tid >> 6, lane = tid & 63;
    size_t base = (size_t)(h * NCHUNK + n);

    __shared__ __align__(16) char LB1[139776];
    unsigned short* QKb  = (unsigned short*)(LB1 + 0);        // 128*104
    unsigned short* Pb   = (unsigned short*)(LB1 + 26624);    // 64*104
    unsigned short* RHSw = (unsigned short*)(LB1 + 39936);    // 96*72
    unsigned short* RHSv = (unsigned short*)(LB1 + 53760);    // 192*72
    unsigned short* Ab   = (unsigned short*)(LB1 + 81408);    // 64*104
    unsigned short* Atb  = (unsigned short*)(LB1 + 94720);    // 64*104
    float*          Pf   = (float*)(LB1 + 121344);            // 64*68 (Ptb slot 108032..121344 kept as overlay space)
    unsigned short* kdT  = (unsigned short*)(LB1 + 81408);    // overlay
    unsigned short* wT   = (unsigned short*)(LB1 + 95232);    // overlay
    unsigned short* uT   = (unsigned short*)(LB1 + 109056);   // overlay
    float* gr_s = (float*)(LB1 + 138752);
    float* gc_s = gr_s + 64;
    float* be_s = gc_s + 64;
    float* egc  = be_s + 64;
    __shared__ __align__(16) float cwS[384 * 4];

    for (int f = tid; f < 384; f += 256) {
        const float* src = (f < 96)  ? (cq + (size_t)(h * 96 + f) * 4)
                         : (f < 192) ? (ck + (size_t)(h * 96 + f - 96) * 4)
                                     : (cv + (size_t)(h * 192 + f - 192) * 4);
        *(float4*)&cwS[f * 4] = *(const float4*)src;
    }
    if (tid < 64) {
        gr_s[tid] = gvec[(size_t)(t0 + tid) * HVN + h];
        be_s[tid] = bvec[(size_t)(t0 + tid) * HVN + h];
    }
    __syncthreads();
    if (tid < 64) {
        float sacc = 0.f;
        for (int j = 0; j <= tid; ++j) sacc += gr_s[j];
        gc_s[tid] = sacc;
    }
    __syncthreads();
    float gl = gc_s[63];
    if (tid < 64) egc[tid] = expf(gl - gc_s[tid]);

    int r = tid >> 2, sub = tid & 3;
    int trow = t0 + r;
    // ---- k ----
    {
        int gc0 = 1536 + h * DKN + sub * 24;
        int lc0 = 96 + sub * 24;
        float kreg[24];
        float ss = 0.f;
#pragma unroll
        for (int i = 0; i < 6; ++i) {
            float4 x0 = (trow >= 3) ? *(const float4*)(Cqkv + (size_t)(trow - 3) * QKVD + gc0 + i * 4) : make_float4(0, 0, 0, 0);
            float4 x1 = (trow >= 2) ? *(const float4*)(Cqkv + (size_t)(trow - 2) * QKVD + gc0 + i * 4) : make_float4(0, 0, 0, 0);
            float4 x2 = (trow >= 1) ? *(const float4*)(Cqkv + (size_t)(trow - 1) * QKVD + gc0 + i * 4) : make_float4(0, 0, 0, 0);
            float4 x3 = *(const float4*)(Cqkv + (size_t)trow * QKVD + gc0 + i * 4);
#pragma unroll
            for (int c = 0; c < 4; ++c) {
                float4 w = *(const float4*)&cwS[(lc0 + i * 4 + c) * 4];
                float xv = ((const float*)&x0)[c] * w.x + ((const float*)&x1)[c] * w.y
                         + ((const float*)&x2)[c] * w.z + ((const float*)&x3)[c] * w.w;
                xv = siluf(xv);
                kreg[i * 4 + c] = xv;
                ss += xv * xv;
            }
        }
        ss += __shfl_xor(ss, 1, 64);
        ss += __shfl_xor(ss, 2, 64);
        float nrm = rsqrtf(ss + EPSF);
        float ebg = be_s[r] * expf(gc_s[r]);
#pragma unroll
        for (int i = 0; i < 24; ++i) {
            float kn = kreg[i] * nrm;
            QKb[r * 104 + sub * 24 + i] = f2bf(kn);
            RHSw[(sub * 24 + i) * 72 + r] = f2bf(kn * ebg);
        }
    }
    // ---- q ----
    {
        int gc0 = h * DKN + sub * 24;
        int lc0 = sub * 24;
        float qreg[24];
        float ss = 0.f;
#pragma unroll
        for (int i = 0; i < 6; ++i) {
            float4 x0 = (trow >= 3) ? *(const float4*)(Cqkv + (size_t)(trow - 3) * QKVD + gc0 + i * 4) : make_float4(0, 0, 0, 0);
            float4 x1 = (trow >= 2) ? *(const float4*)(Cqkv + (size_t)(trow - 2) * QKVD + gc0 + i * 4) : make_float4(0, 0, 0, 0);
            float4 x2 = (trow >= 1) ? *(const float4*)(Cqkv + (size_t)(trow - 1) * QKVD + gc0 + i * 4) : make_float4(0, 0, 0, 0);
            float4 x3 = *(const float4*)(Cqkv + (size_t)trow * QKVD + gc0 + i * 4);
#pragma unroll
            for (int c = 0; c < 4; ++c) {
                float4 w = *(const float4*)&cwS[(lc0 + i * 4 + c) * 4];
                float xv = ((const float*)&x0)[c] * w.x + ((const float*)&x1)[c] * w.y
                         + ((const float*)&x2)[c] * w.z + ((const float*)&x3)[c] * w.w;
                xv = siluf(xv);
                qreg[i * 4 + c] = xv;
                ss += xv * xv;
            }
        }
        ss += __shfl_xor(ss, 1, 64);
        ss += __shfl_xor(ss, 2, 64);
        float nrm = rsqrtf(ss + EPSF) * 0.10206207261596577f;
        float eg = expf(gc_s[r]);
        unsigned short* qgp = qg_bf + base * WQG_ST + r * 104 + sub * 24;
#pragma unroll
        for (int i = 0; i < 24; ++i) {
            float qn = qreg[i] * nrm;
            QKb[(64 + r) * 104 + sub * 24 + i] = f2bf(qn);
            qgp[i] = f2bf(qn * eg);
        }
    }
    // ---- v ----
    {
        int gc0 = 3072 + h * DVN + sub * 48;
        int lc0 = 192 + sub * 48;
        float ber = be_s[r];
#pragma unroll
        for (int i = 0; i < 12; ++i) {
            float4 x0 = (trow >= 3) ? *(const float4*)(Cqkv + (size_t)(trow - 3) * QKVD + gc0 + i * 4) : make_float4(0, 0, 0, 0);
            float4 x1 = (trow >= 2) ? *(const float4*)(Cqkv + (size_t)(trow - 2) * QKVD + gc0 + i * 4) : make_float4(0, 0, 0, 0);
            float4 x2 = (trow >= 1) ? *(const float4*)(Cqkv + (size_t)(trow - 1) * QKVD + gc0 + i * 4) : make_float4(0, 0, 0, 0);
            float4 x3 = *(const float4*)(Cqkv + (size_t)trow * QKVD + gc0 + i * 4);
#pragma unroll
            for (int c = 0; c < 4; ++c) {
                float4 w = *(const float4*)&cwS[(lc0 + i * 4 + c) * 4];
                float xv = ((const float*)&x0)[c] * w.x + ((const float*)&x1)[c] * w.y
                         + ((const float*)&x2)[c] * w.z + ((const float*)&x3)[c] * w.w;
                RHSv[(sub * 48 + i * 4 + c) * 72 + r] = f2bf(siluf(xv) * ber);
            }
        }
    }
    __syncthreads();

    // MFMA1: [Kn;Qn] @ Kn^T -> A (rows<64, P init to I) and attn (rows>=64)
    {
        f32x4 acc1[2][4] = {};
#pragma unroll
        for (int ks = 0; ks < 3; ++ks) {
            int ko = ks * 32 + (lane >> 4) * 8;
            short8 af[2], bfv[4];
#pragma unroll
            for (int rt2 = 0; rt2 < 2; ++rt2)
                af[rt2] = *(const short8*)&QKb[(wave * 32 + rt2 * 16 + (lane & 15)) * 104 + ko];
#pragma unroll
            for (int ct = 0; ct < 4; ++ct)
                bfv[ct] = *(const short8*)&QKb[(ct * 16 + (lane & 15)) * 104 + ko];
#pragma unroll
            for (int rt2 = 0; rt2 < 2; ++rt2)
#pragma unroll
                for (int ct = 0; ct < 4; ++ct)
                    acc1[rt2][ct] = __builtin_amdgcn_mfma_f32_16x16x32_bf16(af[rt2], bfv[ct], acc1[rt2][ct], 0, 0, 0);
        }
#pragma unroll
        for (int rt2 = 0; rt2 < 2; ++rt2)
#pragma unroll
            for (int ct = 0; ct < 4; ++ct)
#pragma unroll
                for (int j = 0; j < 4; ++j) {
                    int rr = wave * 32 + rt2 * 16 + (lane >> 4) * 4 + j;
                    int cc = ct * 16 + (lane & 15);
                    float val = acc1[rt2][ct][j];
                    if (rr < 64) {
                        float av = (rr > cc) ? -be_s[rr] * expf(gc_s[rr] - gc_s[cc]) * val : 0.f;
                        unsigned short ab = f2bf(av);
                        Ab[rr * 104 + cc] = ab;
                        Atb[cc * 104 + rr] = ab;
                        float pv = (rr == cc) ? 1.f : 0.f;   // P0 = I (commuted doubling)
                        Pf[rr * 68 + cc] = pv;
                        Pb[rr * 104 + cc] = f2bf(pv);
                    } else {
                        int ar = rr - 64;
                        float av = (ar >= cc) ? expf(gc_s[ar] - gc_s[cc]) * val : 0.f;
                        at_bf[base * AT_ST + ar * 72 + cc] = f2bf(av);
                    }
                }
    }
    __syncthreads();

    // commuted doubling: 6 levels; per level one MFMA phase computing
    // D = A_k @ A_k  (lev<5)  and  E = P_k + P_k @ A_k; 2 barriers/level.
#pragma unroll 1
    for (int lev = 0; lev < 6; ++lev) {
        f32x4 d[4] = {};
        f32x4 e[4];
#pragma unroll
        for (int ct = 0; ct < 4; ++ct)
#pragma unroll
            for (int j = 0; j < 4; ++j)
                e[ct][j] = Pf[(wave * 16 + (lane >> 4) * 4 + j) * 68 + ct * 16 + (lane & 15)];
#pragma unroll
        for (int ks = 0; ks < 2; ++ks) {
            int ko = ks * 32 + (lane >> 4) * 8;
            short8 aA = *(const short8*)&Ab[(wave * 16 + (lane & 15)) * 104 + ko];
            short8 aP = *(const short8*)&Pb[(wave * 16 + (lane & 15)) * 104 + ko];
#pragma unroll
            for (int ct = 0; ct < 4; ++ct) {
                short8 bAt = *(const short8*)&Atb[(ct * 16 + (lane & 15)) * 104 + ko];
                if (lev < 5) d[ct] = __builtin_amdgcn_mfma_f32_16x16x32_bf16(aA, bAt, d[ct], 0, 0, 0);
                e[ct] = __builtin_amdgcn_mfma_f32_16x16x32_bf16(aP, bAt, e[ct], 0, 0, 0);
            }
        }
        __syncthreads();
#pragma unroll
        for (int ct = 0; ct < 4; ++ct)
#pragma unroll
            for (int j = 0; j < 4; ++j) {
                int rr = wave * 16 + (lane >> 4) * 4 + j;
                int cc = ct * 16 + (lane & 15);
                if (lev < 5) {
                    unsigned short hb = f2bf(d[ct][j]);
                    Ab[rr * 104 + cc] = hb;
                    Atb[cc * 104 + rr] = hb;
                }
                float pv = e[ct][j];
                Pf[rr * 68 + cc] = pv;
                Pb[rr * 104 + cc] = f2bf(pv);
            }
        __syncthreads();
    }
    // overlay kdT/wT/uT (Ab/Atb/Ptb-slot/Pf dead)
    for (int f = tid; f < 6144; f += 256) {
        int d = f >> 6, tt = f & 63;
        kdT[d * 72 + tt] = f2bf(bf2f(QKb[tt * 104 + d]) * egc[tt]);
    }

#pragma unroll 1
    for (int i = 0; i < 18; ++i) {
        int id = wave * 18 + i;
        int rt = id & 3, ct = id >> 2;
        f32x4 o4 = {};
#pragma unroll
        for (int ks = 0; ks < 2; ++ks) {
            int ko = ks * 32 + (lane >> 4) * 8;
            short8 a0 = *(const short8*)&Pb[(rt * 16 + (lane & 15)) * 104 + ko];
            short8 b0 = (ct < 12)
                ? *(const short8*)&RHSv[(ct * 16 + (lane & 15)) * 72 + ko]
                : *(const short8*)&RHSw[((ct - 12) * 16 + (lane & 15)) * 72 + ko];
            o4 = __builtin_amdgcn_mfma_f32_16x16x32_bf16(a0, b0, o4, 0, 0, 0);
        }
#pragma unroll
        for (int j = 0; j < 4; ++j) {
            int rr = rt * 16 + (lane >> 4) * 4 + j;
            int nn = ct * 16 + (lane & 15);
            if (ct < 12) {
                u_ws[base * U_ST + rr * 192 + nn] = o4[j];
                uT[nn * 72 + rr] = f2bf(o4[j]);
            } else {
                w_bf[base * WQG_ST + rr * 104 + (nn - 192)] = f2bf(-o4[j]);
                wT[(nn - 192) * 72 + rr] = f2bf(o4[j]);
            }
        }
    }
    __syncthreads();

    // fused tprep: Tn = e^gl I - kd^T w (bf16, stride-104), Ct = u^T kd (bf16)
    float eglv = expf(gl);
#pragma unroll 1
    for (int q = 0; q < 27; ++q) {
        int id = wave * 27 + q;
        f32x4 acc = {};
        if (id < 36) {
            int jt = id / 6, kt = id % 6;
#pragma unroll
            for (int ks = 0; ks < 2; ++ks) {
                int ko = ks * 32 + (lane >> 4) * 8;
                short8 a0 = *(const short8*)&kdT[(jt * 16 + (lane & 15)) * 72 + ko];
                short8 b0 = *(const short8*)&wT[(kt * 16 + (lane & 15)) * 72 + ko];
                acc = __builtin_amdgcn_mfma_f32_16x16x32_bf16(a0, b0, acc, 0, 0, 0);
            }
#pragma unroll
            for (int rr = 0; rr < 4; ++rr) {
                int j = jt * 16 + (lane >> 4) * 4 + rr;
                int k = kt * 16 + (lane & 15);
                float val = -acc[rr];
                if (j == k) val += eglv;
                Tn[base * TN_STRIDE + j * 104 + k] = f2bf(val);
            }
        } else {
            int cid = id - 36;
            int it = cid / 6, jt = cid % 6;
#pragma unroll
            for (int ks = 0; ks < 2; ++ks) {
                int ko = ks * 32 + (lane >> 4) * 8;
                short8 a0 = *(const short8*)&uT[(it * 16 + (lane & 15)) * 72 + ko];
                short8 b0 = *(const short8*)&kdT[(jt * 16 + (lane & 15)) * 72 + ko];
                acc = __builtin_amdgcn_mfma_f32_16x16x32_bf16(a0, b0, acc, 0, 0, 0);
            }
#pragma unroll
            for (int rr = 0; rr < 4; ++rr)
                Ct[base * CT_ST + (size_t)(it * 16 + (lane >> 4) * 4 + rr) * 96 + jt * 16 + (lane & 15)] = f2bf(acc[rr]);
        }
    }
}

// ---------------- mscan ----------------
__global__ __launch_bounds__(128) void mscan(const unsigned short* __restrict__ Ct,
                                             const unsigned short* __restrict__ Tn,
                                             unsigned short* __restrict__ s_bf) {
    int rg = blockIdx.x, h = blockIdx.y;
    int tid = threadIdx.x, wave = tid >> 6, lane = tid & 63;
    __shared__ __align__(16) unsigned short St[48 * 104];
    __shared__ __align__(16) unsigned short TnB[2][TN_STRIDE];
    __shared__ __align__(16) unsigned short CtB[2][48 * 96];
    for (int i = tid; i < 48 * 104; i += 128) St[i] = 0;

    {
        const char* cp = (const char*)(Ct + (size_t)(h * NCHUNK) * CT_ST + rg * (48 * 96));
        const char* tp = (const char*)(Tn + (size_t)(h * NCHUNK) * TN_STRIDE);
        for (int q = wave; q < 9; q += 2)
            gld_lds16(cp + (size_t)q * 1024 + lane * 16, (char*)&CtB[0][0] + (size_t)q * 1024);
#pragma unroll
        for (int q = 0; q < 10; ++q) {
            size_t o = (size_t)(wave * 10 + q) * 1024 + lane * 16;
            gld_lds16(tp + o, (char*)&TnB[0][0] + (size_t)(wave * 10 + q) * 1024);
        }
    }
    f32x4 acc[3][3];
    int colw = wave * 48;
    __syncthreads();

#pragma unroll 1
    for (int n = 0; n < NCHUNK; ++n) {
        size_t base = (size_t)(h * NCHUNK + n);
        int cur = n & 1;
        if (n + 1 < NCHUNK) {
            const char* cp = (const char*)(Ct + (base + 1) * CT_ST + rg * (48 * 96));
            const char* tp = (const char*)(Tn + (base + 1) * TN_STRIDE);
            for (int q = wave; q < 9; q += 2)
                gld_lds16(cp + (size_t)q * 1024 + lane * 16, (char*)&CtB[cur ^ 1][0] + (size_t)q * 1024);
#pragma unroll
            for (int q = 0; q < 10; ++q) {
                size_t o = (size_t)(wave * 10 + q) * 1024 + lane * 16;
                gld_lds16(tp + o, (char*)&TnB[cur ^ 1][0] + (size_t)(wave * 10 + q) * 1024);
            }
        }
        {
            unsigned short* sp = s_bf + base * S_ST + rg * 4992;
            for (int f = tid; f < 624; f += 128)
                *(short8*)(sp + f * 8) = *(const short8*)&St[f * 8];
        }
#pragma unroll
        for (int it = 0; it < 3; ++it)
#pragma unroll
            for (int jt = 0; jt < 3; ++jt) {
                int irow = it * 16 + (lane >> 4) * 4;
                int col = colw + jt * 16 + (lane & 15);
#pragma unroll
                for (int r = 0; r < 4; ++r)
                    acc[it][jt][r] = bf2f(CtB[cur][(irow + r) * 96 + col]);
            }
#pragma unroll
        for (int ks = 0; ks < 3; ++ks) {
            int ko = ks * 32 + (lane >> 4) * 8;
            short8 af[3], bfv[3];
#pragma unroll
            for (int it = 0; it < 3; ++it)
                af[it] = *(const short8*)&St[(it * 16 + (lane & 15)) * 104 + ko];
#pragma unroll
            for (int jt = 0; jt < 3; ++jt)
                bfv[jt] = *(const short8*)&TnB[cur][(colw + jt * 16 + (lane & 15)) * 104 + ko];
#pragma unroll
            for (int it = 0; it < 3; ++it)
#pragma unroll
                for (int jt = 0; jt < 3; ++jt)
                    acc[it][jt] = __builtin_amdgcn_mfma_f32_16x16x32_bf16(af[it], bfv[jt], acc[it][jt], 0, 0, 0);
        }
        __syncthreads();
#pragma unroll
        for (int it = 0; it < 3; ++it)
#pragma unroll
            for (int jt = 0; jt < 3; ++jt)
#pragma unroll
                for (int r = 0; r < 4; ++r)
                    St[(it * 16 + (lane >> 4) * 4 + r) * 104 + colw + jt * 16 + (lane & 15)] = f2bf(acc[it][jt][r]);
        __syncthreads();
    }
}

// ---------------- phase2b (MFMA) + fused gate/RMSNorm -> obf ----------------
#define P2_ST 0
#define P2_W  39936
#define P2_QG 53248
#define P2_AT 66560
#define P2_U  75776
#define P2_VN 125952
__global__ __launch_bounds__(256) void phase2b_mfma(const unsigned short* __restrict__ s_bf,
                                                    const unsigned short* __restrict__ w_bf,
                                                    const unsigned short* __restrict__ qg_bf,
                                                    const unsigned short* __restrict__ at_bf,
                                                    const float* __restrict__ u_ws,
                                                    const unsigned short* __restrict__ Cgate,
                                                    const float* __restrict__ nw,
                                                    unsigned short* __restrict__ obf) {
    __shared__ __align__(16) char LB[153600];
    unsigned short* StB = (unsigned short*)(LB + P2_ST);
    unsigned short* wB  = (unsigned short*)(LB + P2_W);
    unsigned short* qgB = (unsigned short*)(LB + P2_QG);
    unsigned short* atB = (unsigned short*)(LB + P2_AT);
    float* uF           = (float*)(LB + P2_U);
    unsigned short* vnB = (unsigned short*)(LB + P2_VN);
    int n = blockIdx.x, h = blockIdx.y;
    size_t base = (size_t)(h * NCHUNK + n);
    int tid = threadIdx.x, wave = tid >> 6, lane = tid & 63;
    int i0w = wave * 48;
    {
        const char* sp = (const char*)(s_bf + base * S_ST);
        const char* wp = (const char*)(w_bf + base * WQG_ST);
        const char* qp = (const char*)(qg_bf + base * WQG_ST);
        const char* ap = (const char*)(at_bf + base * AT_ST);
        for (int q = wave; q < 39; q += 4)
            gld_lds16(sp + (size_t)q * 1024 + lane * 16, LB + P2_ST + (size_t)q * 1024);
        for (int q = wave; q < 13; q += 4)
            gld_lds16(wp + (size_t)q * 1024 + lane * 16, LB + P2_W + (size_t)q * 1024);
        for (int q = wave; q < 13; q += 4)
            gld_lds16(qp + (size_t)q * 1024 + lane * 16, LB + P2_QG + (size_t)q * 1024);
        for (int q = wave; q < 9; q += 4)
            gld_lds16(ap + (size_t)q * 1024 + lane * 16, LB + P2_AT + (size_t)q * 1024);
    }
    {
        const float* up = u_ws + base * U_ST;
        for (int f = tid; f < 3072; f += 256) {
            int t = f / 48, c4 = (f % 48) * 4;
            *(float4*)&uF[t * 196 + c4] = *(const float4*)(up + t * 192 + c4);
        }
    }
    __syncthreads();
    {
        f32x4 acc[3][4];
#pragma unroll
        for (int it = 0; it < 3; ++it)
#pragma unroll
            for (int jt = 0; jt < 4; ++jt)
#pragma unroll
                for (int r = 0; r < 4; ++r)
                    acc[it][jt][r] = uF[(jt * 16 + (lane & 15)) * 196 + i0w + it * 16 + (lane >> 4) * 4 + r];
#pragma unroll
        for (int ks = 0; ks < 3; ++ks) {
            int ko = ks * 32 + (lane >> 4) * 8;
            short8 af[3], bfv[4];
#pragma unroll
            for (int it = 0; it < 3; ++it)
                af[it] = *(const short8*)&StB[(i0w + it * 16 + (lane & 15)) * 104 + ko];
#pragma unroll
            for (int jt = 0; jt < 4; ++jt)
                bfv[jt] = *(const short8*)&wB[(jt * 16 + (lane & 15)) * 104 + ko];
#pragma unroll
            for (int it = 0; it < 3; ++it)
#pragma unroll
                for (int jt = 0; jt < 4; ++jt)
                    acc[it][jt] = __builtin_amdgcn_mfma_f32_16x16x32_bf16(af[it], bfv[jt], acc[it][jt], 0, 0, 0);
        }
#pragma unroll
        for (int it = 0; it < 3; ++it)
#pragma unroll
            for (int jt = 0; jt < 4; ++jt)
#pragma unroll
                for (int r = 0; r < 4; ++r)
                    vnB[(i0w + it * 16 + (lane >> 4) * 4 + r) * 72 + jt * 16 + (lane & 15)] = f2bf(acc[it][jt][r]);
    }
    f32x4 acc2[3][4] = {};
#pragma unroll
    for (int ks = 0; ks < 3; ++ks) {
        int ko = ks * 32 + (lane >> 4) * 8;
        short8 af[3], bfv[4];
#pragma unroll
        for (int it = 0; it < 3; ++it)
            af[it] = *(const short8*)&StB[(i0w + it * 16 + (lane & 15)) * 104 + ko];
#pragma unroll
        for (int jt = 0; jt < 4; ++jt)
            bfv[jt] = *(const short8*)&qgB[(jt * 16 + (lane & 15)) * 104 + ko];
#pragma unroll
        for (int it = 0; it < 3; ++it)
#pragma unroll
            for (int jt = 0; jt < 4; ++jt)
                acc2[it][jt] = __builtin_amdgcn_mfma_f32_16x16x32_bf16(af[it], bfv[jt], acc2[it][jt], 0, 0, 0);
    }
#pragma unroll
    for (int ks = 0; ks < 2; ++ks) {
        int ko = ks * 32 + (lane >> 4) * 8;
        short8 af[3], bfv[4];
#pragma unroll
        for (int it = 0; it < 3; ++it)
            af[it] = *(const short8*)&vnB[(i0w + it * 16 + (lane & 15)) * 72 + ko];
#pragma unroll
        for (int jt = 0; jt < 4; ++jt)
            bfv[jt] = *(const short8*)&atB[(jt * 16 + (lane & 15)) * 72 + ko];
#pragma unroll
        for (int it = 0; it < 3; ++it)
#pragma unroll
            for (int jt = 0; jt < 4; ++jt)
                acc2[it][jt] = __builtin_amdgcn_mfma_f32_16x16x32_bf16(af[it], bfv[jt], acc2[it][jt], 0, 0, 0);
    }
    __syncthreads();
    float* oF = (float*)(LB + 0);
#pragma unroll
    for (int it = 0; it < 3; ++it)
#pragma unroll
        for (int jt = 0; jt < 4; ++jt)
#pragma unroll
            for (int r = 0; r < 4; ++r)
                oF[(i0w + it * 16 + (lane >> 4) * 4 + r) * 68 + jt * 16 + (lane & 15)] = acc2[it][jt][r];
    __syncthreads();

    float* ssq = (float*)(LB + 131072);
    float* rno = (float*)(LB + 132096);
    int jj = tid >> 2, qq = tid & 3;
    int t0 = n * CHUNKN;
    {
        const unsigned short* gp = Cgate + (size_t)(t0 + jj) * VDIMN + h * DVN + qq * 48;
        float ss = 0.f;
#pragma unroll 4
        for (int m = 0; m < 48; ++m) {
            int i = qq * 48 + m;
            float x = oF[i * 68 + jj];
            float g = bf2f(gp[m]);
            float xv = x * siluf(g);
            oF[i * 68 + jj] = xv;
            ss += xv * xv;
        }
        ssq[jj * 4 + qq] = ss;
    }
    __syncthreads();
    if (tid < 64) {
        float tot = ssq[tid * 4] + ssq[tid * 4 + 1] + ssq[tid * 4 + 2] + ssq[tid * 4 + 3];
        rno[tid] = rsqrtf(tot * (1.f / 192.f) + EPSF);
    }
    __syncthreads();
    {
        float rr2 = rno[jj];
        unsigned short* op = obf + (size_t)(t0 + jj) * VDIMN + h * DVN + qq * 48;
#pragma unroll 4
        for (int m = 0; m < 48; ++m) {
            int i = qq * 48 + m;
            op[m] = f2bf(oF[i * 68 + jj] * rr2 * nw[i]);
        }
    }
}

extern "C" void kernel_launch(void* const* d_in, const int* in_sizes, int n_in,
                              void* d_out, int out_size, void* d_ws, size_t ws_size,
                              hipStream_t stream) {
    (void)in_sizes; (void)n_in; (void)out_size;
    const float* X    = (const float*)d_in[0];
    const float* Wq   = (const float*)d_in[1];
    const float* Wk   = (const float*)d_in[2];
    const float* Wv   = (const float*)d_in[3];
    const float* Wb   = (const float*)d_in[4];
    const float* Wa   = (const float*)d_in[5];
    const float* Wg   = (const float*)d_in[6];
    const float* Wo   = (const float*)d_in[7];
    const float* cq   = (const float*)d_in[8];
    const float* ck   = (const float*)d_in[9];
    const float* cv   = (const float*)d_in[10];
    const float* Alog = (const float*)d_in[11];
    const float* dtb  = (const float*)d_in[12];
    const float* nw   = (const float*)d_in[13];

    const size_t OFF_XBF   = 0;
    const size_t OFF_WALLT = 8388608;
    const size_t OFF_WOT   = 46137344;
    const size_t OFF_CQKV  = 58720256;
    const size_t OFF_CGATE = 109051904;
    const size_t OFF_CT    = 134217728;
    const size_t OFF_TN    = OFF_CT + 37748736;
    const size_t OFF_GVEC  = 184549376;
    const size_t OFF_BVEC  = 184680448;
    const size_t OFF_U     = 184819712;
    const size_t OFF_W     = 209985536;
    const size_t OFF_QG    = 222568448;
    const size_t OFF_AT    = OFF_XBF;
    const size_t OFF_S     = OFF_CQKV;
    const size_t OFF_OBF   = OFF_WALLT + 25165824;
    const size_t OFF_OPART = OFF_CQKV;
    const size_t NEEDED    = 235151360;
    if (ws_size < NEEDED) return;

    char* ws = (char*)d_ws;
    unsigned short* Xbf   = (unsigned short*)(ws + OFF_XBF);
    unsigned short* WallT = (unsigned short*)(ws + OFF_WALLT);
    unsigned short* WoT   = (unsigned short*)(ws + OFF_WOT);
    float* Cqkv  = (float*)(ws + OFF_CQKV);
    unsigned short* Cgate = (unsigned short*)(ws + OFF_CGATE);
    float* gvec  = (float*)(ws + OFF_GVEC);
    float* bvec  = (float*)(ws + OFF_BVEC);
    float* u_ws  = (float*)(ws + OFF_U);
    unsigned short* w_bf  = (unsigned short*)(ws + OFF_W);
    unsigned short* qg_bf = (unsigned short*)(ws + OFF_QG);
    unsigned short* at_bf = (unsigned short*)(ws + OFF_AT);
    unsigned short* Ct    = (unsigned short*)(ws + OFF_CT);
    unsigned short* Tn    = (unsigned short*)(ws + OFF_TN);
    unsigned short* s_bf  = (unsigned short*)(ws + OFF_S);
    unsigned short* obf   = (unsigned short*)(ws + OFF_OBF);
    float* opart = (float*)(ws + OFF_OPART);

    // merged: beta/g (+X cast) and weight transposes
    prep_all<<<8192, 256, 0, stream>>>(X, Wb, Wa, Alog, dtb, bvec, gvec, Xbf,
                                       Wq, Wk, Wv, Wg, Wo, WallT, WoT);

    // fused QKV (f32) + gate (bf16) projection, 2-phase BK=64
    gemm_bt2<<<dim3(9216 / 128, 2048 / 128), 256, 0, stream>>>(Xbf, WallT,
                                                               Cqkv, QKVD, QKVD / 128,
                                                               Cgate, VDIMN, 2048, 2048);

    phase1_mfma<<<dim3(NCHUNK, HVN), 256, 0, stream>>>(Cqkv, cq, ck, cv, gvec, bvec,
                                                       u_ws, w_bf, qg_bf, at_bf, Ct, Tn);
    mscan<<<dim3(4, HVN), 128, 0, stream>>>(Ct, Tn, s_bf);
    phase2b_mfma<<<dim3(NCHUNK, HVN), 256, 0, stream>>>(s_bf, w_bf, qg_bf, at_bf, u_ws,
                                                        Cgate, nw, obf);

    // output GEMM split-K=3 (2-phase BK=64) + deterministic fixup
    gemm_btk<<<dim3(2048 / 128, 2048 / 128, 3), 256, 0, stream>>>(obf, WoT, (float*)d_out, opart,
                                                                  2048, 2048, 3072);
    addk<<<4096, 256, 0, stream>>>((float*)d_out, opart, 2048 * 2048);
}

// Round 15
// 400.794 us; speedup vs baseline: 1.0131x; 1.0131x over previous
//
#include <hip/hip_runtime.h>
#include <math.h>

#define T_LEN 2048
#define HIDN  2048
#define HKN   16
#define DKN   96
#define HVN   16
#define DVN   192
#define KDIMN 1536
#define VDIMN 3072
#define QKVD  6144
#define CHUNKN 64
#define NCHUNK 32
#define EPSF 1e-6f
#define TN_STRIDE 10240
#define WQG_ST 6656
#define AT_ST  4608
#define CT_ST  18432
#define S_ST   19968
#define U_ST   12288

typedef __attribute__((ext_vector_type(8))) short short8;
typedef __attribute__((ext_vector_type(4))) float f32x4;

__device__ __forceinline__ unsigned short f2bf(float f) {
    unsigned int u = __float_as_uint(f);
    unsigned int r = (u + 0x7FFFu + ((u >> 16) & 1u)) >> 16;
    return (unsigned short)r;
}
__device__ __forceinline__ float bf2f(unsigned short u) {
    return __uint_as_float(((unsigned int)u) << 16);
}
__device__ __forceinline__ float siluf(float x) { return x / (1.f + expf(-x)); }

__device__ __forceinline__ void gld_lds16(const void* g, void* l) {
    __builtin_amdgcn_global_load_lds((const __attribute__((address_space(1))) unsigned int*)g,
                                     (__attribute__((address_space(3))) unsigned int*)l, 16, 0, 0);
}

// ---------------- merged prep: beta/g projection (+X cast) AND weight transposes ----------------
__global__ __launch_bounds__(256) void prep_all(
    const float* __restrict__ X,
    const float* __restrict__ Wb, const float* __restrict__ Wa,
    const float* __restrict__ A_log, const float* __restrict__ dtb,
    float* __restrict__ bvec, float* __restrict__ gvec, unsigned short* __restrict__ Xbf,
    const float* __restrict__ Wq, const float* __restrict__ Wk,
    const float* __restrict__ Wv, const float* __restrict__ Wg,
    const float* __restrict__ Wo,
    unsigned short* __restrict__ WallT, unsigned short* __restrict__ WoT) {
    __shared__ float tile[64][65];
    __shared__ float red[4][8][4];
    int bid = blockIdx.x;
    int tid = threadIdx.x;
    if (bid < 2048) {
        int t = bid;
        int cg = tid & 7, ks = tid >> 3;
        int wave = tid >> 6, lane = tid & 63;
        const float* xr = X + (size_t)t * HIDN;
        const float* Wsel = (cg < 4) ? Wb : Wa;
        int cc = (cg & 3) * 4;
        float ax = 0.f, ay = 0.f, az = 0.f, aw = 0.f;
#pragma unroll 4
        for (int i = 0; i < 16; ++i) {
            int k = (ks + 32 * i) * 4;
            float4 xv = *(const float4*)(xr + k);
            if (cg == 0) {
                ushort4 xo;
                xo.x = f2bf(xv.x); xo.y = f2bf(xv.y); xo.z = f2bf(xv.z); xo.w = f2bf(xv.w);
                *(ushort4*)(Xbf + (size_t)t * HIDN + k) = xo;
            }
            float4 w0 = *(const float4*)(Wsel + (size_t)(k + 0) * 16 + cc);
            float4 w1 = *(const float4*)(Wsel + (size_t)(k + 1) * 16 + cc);
            float4 w2 = *(const float4*)(Wsel + (size_t)(k + 2) * 16 + cc);
            float4 w3 = *(const float4*)(Wsel + (size_t)(k + 3) * 16 + cc);
            ax += xv.x * w0.x + xv.y * w1.x + xv.z * w2.x + xv.w * w3.x;
            ay += xv.x * w0.y + xv.y * w1.y + xv.z * w2.y + xv.w * w3.y;
            az += xv.x * w0.z + xv.y * w1.z + xv.z * w2.z + xv.w * w3.z;
            aw += xv.x * w0.w + xv.y * w1.w + xv.z * w2.w + xv.w * w3.w;
        }
#pragma unroll
        for (int off = 8; off <= 32; off <<= 1) {
            ax += __shfl_xor(ax, off, 64);
            ay += __shfl_xor(ay, off, 64);
            az += __shfl_xor(az, off, 64);
            aw += __shfl_xor(aw, off, 64);
        }
        if ((lane >> 3) == 0) {
            red[wave][cg][0] = ax; red[wave][cg][1] = ay;
            red[wave][cg][2] = az; red[wave][cg][3] = aw;
        }
        __syncthreads();
        if (tid < 8) {
            float tot[4];
#pragma unroll
            for (int j = 0; j < 4; ++j)
                tot[j] = red[0][tid][j] + red[1][tid][j] + red[2][tid][j] + red[3][tid][j];
            int c0 = (tid & 3) * 4;
            if (tid < 4) {
#pragma unroll
                for (int j = 0; j < 4; ++j)
                    bvec[(size_t)t * 16 + c0 + j] = 2.f / (1.f + expf(-tot[j]));
            } else {
#pragma unroll
                for (int j = 0; j < 4; ++j) {
                    float a = tot[j] + dtb[c0 + j];
                    float sp = (a > 20.f) ? a : log1pf(expf(a));
                    gvec[(size_t)t * 16 + c0 + j] = -expf(A_log[c0 + j]) * sp;
                }
            }
        }
    } else {
        int b2 = bid - 2048;
        const float* W; unsigned short* Wt; int K, N, l;
        if (b2 < 768)       { W = Wq; Wt = WallT;                       K = 2048; N = 1536; l = b2; }
        else if (b2 < 1536) { W = Wk; Wt = WallT + (size_t)1536 * 2048; K = 2048; N = 1536; l = b2 - 768; }
        else if (b2 < 3072) { W = Wv; Wt = WallT + (size_t)3072 * 2048; K = 2048; N = 3072; l = b2 - 1536; }
        else if (b2 < 4608) { W = Wg; Wt = WallT + (size_t)6144 * 2048; K = 2048; N = 3072; l = b2 - 3072; }
        else                { W = Wo; Wt = WoT;                         K = 3072; N = 2048; l = b2 - 4608; }
        int nbx = N >> 6;
        int n0 = (l % nbx) * 64, k0 = (l / nbx) * 64;
        int tx = tid & 63, ty = tid >> 6;
        for (int r = ty; r < 64; r += 4) tile[r][tx] = W[(size_t)(k0 + r) * N + n0 + tx];
        __syncthreads();
        for (int r = ty; r < 64; r += 4) Wt[(size_t)(n0 + r) * K + k0 + tx] = f2bf(tile[tx][r]);
    }
}

// ---------------- fused projection GEMM, 2-phase double-buffered LDS (BK=32) ----------------
__global__ __launch_bounds__(256) void gemm_bt2(const unsigned short* __restrict__ A,
                                                const unsigned short* __restrict__ Bt,
                                                float* __restrict__ C1, int ld1, int nblk1,
                                                unsigned short* __restrict__ C2, int ld2,
                                                int M, int K) {
    __shared__ __align__(16) unsigned short As[2][128 * 32];
    __shared__ __align__(16) unsigned short Bs[2][128 * 32];
    int tid = threadIdx.x;
    int wave = tid >> 6, lane = tid & 63;
    int bm = blockIdx.y, bn = blockIdx.x;
    f32x4 acc[4][4] = {};
    int wr = wave >> 1, wc = wave & 1;
    int rstage = wave * 32 + (lane >> 2);
    int cstage = (lane & 3) * 8;
    const size_t a_row0 = (size_t)bm * 128;
    const size_t b_row0 = (size_t)bn * 128;
    const unsigned short* gaBase = A + (a_row0 + rstage) * (size_t)K + cstage;
    const unsigned short* gbBase = Bt + (b_row0 + rstage) * (size_t)K + cstage;
    int row_a[4], row_b[4];
#pragma unroll
    for (int i = 0; i < 4; ++i) {
        row_a[i] = wr * 64 + i * 16 + (lane & 15);
        row_b[i] = wc * 64 + i * 16 + (lane & 15);
    }
    int koff = (lane >> 4) * 8;
    int niter = K >> 5;
    {
        unsigned short* ab = &As[0][wave * 1024];
        unsigned short* bb = &Bs[0][wave * 1024];
        gld_lds16(gaBase, ab);
        gld_lds16(gaBase + (size_t)16 * K, ab + 512);
        gld_lds16(gbBase, bb);
        gld_lds16(gbBase + (size_t)16 * K, bb + 512);
    }
    __syncthreads();
    for (int i = 0; i < niter; ++i) {
        int cur = i & 1;
        if (i + 1 < niter) {
            int k0 = (i + 1) * 32;
            unsigned short* ab = &As[cur ^ 1][wave * 1024];
            unsigned short* bb = &Bs[cur ^ 1][wave * 1024];
            gld_lds16(gaBase + k0, ab);
            gld_lds16(gaBase + k0 + (size_t)16 * K, ab + 512);
            gld_lds16(gbBase + k0, bb);
            gld_lds16(gbBase + k0 + (size_t)16 * K, bb + 512);
        }
        short8 af[4], bfr[4];
#pragma unroll
        for (int mi = 0; mi < 4; ++mi) af[mi] = *(const short8*)&As[cur][row_a[mi] * 32 + koff];
#pragma unroll
        for (int ni = 0; ni < 4; ++ni) bfr[ni] = *(const short8*)&Bs[cur][row_b[ni] * 32 + koff];
#pragma unroll
        for (int mi = 0; mi < 4; ++mi)
#pragma unroll
            for (int ni = 0; ni < 4; ++ni)
                acc[mi][ni] = __builtin_amdgcn_mfma_f32_16x16x32_bf16(af[mi], bfr[ni], acc[mi][ni], 0, 0, 0);
        __syncthreads();
    }
    if (bn < nblk1) {
        int colb = bn * 128;
#pragma unroll
        for (int mi = 0; mi < 4; ++mi) {
            int rbase = bm * 128 + wr * 64 + mi * 16 + (lane >> 4) * 4;
#pragma unroll
            for (int ni = 0; ni < 4; ++ni) {
                int col = colb + wc * 64 + ni * 16 + (lane & 15);
#pragma unroll
                for (int j = 0; j < 4; ++j)
                    C1[(size_t)(rbase + j) * ld1 + col] = acc[mi][ni][j];
            }
        }
    } else {
        int colb = (bn - nblk1) * 128;
#pragma unroll
        for (int mi = 0; mi < 4; ++mi) {
            int rbase = bm * 128 + wr * 64 + mi * 16 + (lane >> 4) * 4;
#pragma unroll
            for (int ni = 0; ni < 4; ++ni) {
                int col = colb + wc * 64 + ni * 16 + (lane & 15);
#pragma unroll
                for (int j = 0; j < 4; ++j)
                    C2[(size_t)(rbase + j) * ld2 + col] = f2bf(acc[mi][ni][j]);
            }
        }
    }
}

// ---------------- split-K GEMM (SPLIT=3), 2-phase double-buffered LDS (BK=32) ----------------
__global__ __launch_bounds__(256) void gemm_btk(const unsigned short* __restrict__ A,
                                                const unsigned short* __restrict__ Bt,
                                                float* __restrict__ C, float* __restrict__ Cp,
                                                int M, int N, int K) {
    __shared__ __align__(16) unsigned short As[2][128 * 32];
    __shared__ __align__(16) unsigned short Bs[2][128 * 32];
    int tid = threadIdx.x;
    int wave = tid >> 6, lane = tid & 63;
    int bm = blockIdx.y, bn = blockIdx.x, kz = blockIdx.z;
    int kchunk = K / 3;
    int kbeg = kz * kchunk;
    f32x4 acc[4][4] = {};
    int wr = wave >> 1, wc = wave & 1;
    int rstage = wave * 32 + (lane >> 2);
    int cstage = (lane & 3) * 8;
    const size_t a_row0 = (size_t)bm * 128;
    const size_t b_row0 = (size_t)bn * 128;
    const unsigned short* gaBase = A + (a_row0 + rstage) * (size_t)K + kbeg + cstage;
    const unsigned short* gbBase = Bt + (b_row0 + rstage) * (size_t)K + kbeg + cstage;
    int row_a[4], row_b[4];
#pragma unroll
    for (int i = 0; i < 4; ++i) {
        row_a[i] = wr * 64 + i * 16 + (lane & 15);
        row_b[i] = wc * 64 + i * 16 + (lane & 15);
    }
    int koff = (lane >> 4) * 8;
    int niter = kchunk >> 5;
    {
        unsigned short* ab = &As[0][wave * 1024];
        unsigned short* bb = &Bs[0][wave * 1024];
        gld_lds16(gaBase, ab);
        gld_lds16(gaBase + (size_t)16 * K, ab + 512);
        gld_lds16(gbBase, bb);
        gld_lds16(gbBase + (size_t)16 * K, bb + 512);
    }
    __syncthreads();
    for (int i = 0; i < niter; ++i) {
        int cur = i & 1;
        if (i + 1 < niter) {
            int k0 = (i + 1) * 32;
            unsigned short* ab = &As[cur ^ 1][wave * 1024];
            unsigned short* bb = &Bs[cur ^ 1][wave * 1024];
            gld_lds16(gaBase + k0, ab);
            gld_lds16(gaBase + k0 + (size_t)16 * K, ab + 512);
            gld_lds16(gbBase + k0, bb);
            gld_lds16(gbBase + k0 + (size_t)16 * K, bb + 512);
        }
        short8 af[4], bfr[4];
#pragma unroll
        for (int mi = 0; mi < 4; ++mi) af[mi] = *(const short8*)&As[cur][row_a[mi] * 32 + koff];
#pragma unroll
        for (int ni = 0; ni < 4; ++ni) bfr[ni] = *(const short8*)&Bs[cur][row_b[ni] * 32 + koff];
#pragma unroll
        for (int mi = 0; mi < 4; ++mi)
#pragma unroll
            for (int ni = 0; ni < 4; ++ni)
                acc[mi][ni] = __builtin_amdgcn_mfma_f32_16x16x32_bf16(af[mi], bfr[ni], acc[mi][ni], 0, 0, 0);
        __syncthreads();
    }
    float* Cout = (kz == 0) ? C : (Cp + (size_t)(kz - 1) * M * N);
#pragma unroll
    for (int mi = 0; mi < 4; ++mi) {
        int rbase = bm * 128 + wr * 64 + mi * 16 + (lane >> 4) * 4;
#pragma unroll
        for (int ni = 0; ni < 4; ++ni) {
            int col = bn * 128 + wc * 64 + ni * 16 + (lane & 15);
#pragma unroll
            for (int j = 0; j < 4; ++j)
                Cout[(size_t)(rbase + j) * N + col] = acc[mi][ni][j];
        }
    }
}

// ---------------- addk: out += p0 + p1 ----------------
__global__ void addk(float* __restrict__ out, const float* __restrict__ p, int n) {
    int i = (blockIdx.x * blockDim.x + threadIdx.x) * 4;
    if (i >= n) return;
    float4 a = *(const float4*)(out + i);
    float4 b = *(const float4*)(p + i);
    float4 c = *(const float4*)(p + n + i);
    a.x += b.x + c.x; a.y += b.y + c.y; a.z += b.z + c.z; a.w += b.w + c.w;
    *(float4*)(out + i) = a;
}

// ---------------- phase 1 (MFMA): fused conv+SiLU + WY-prep + tprep ----------------
// commuted doubling: P_{k+1} = P_k + P_k@A_k (6 levels, D and E share one phase)
__global__ __launch_bounds__(256) void phase1_mfma(
    const float* __restrict__ Cqkv,
    const float* __restrict__ cq, const float* __restrict__ ck, const float* __restrict__ cv,
    const float* __restrict__ gvec, const float* __restrict__ bvec,
    float* __restrict__ u_ws, unsigned short* __restrict__ w_bf,
    unsigned short* __restrict__ qg_bf, unsigned short* __restrict__ at_bf,
    unsigned short* __restrict__ Ct, unsigned short* __restrict__ Tn) {
    int n = blockIdx.x, h = blockIdx.y;
    int t0 = n * CHUNKN;
    int tid = threadIdx.x;
    int wave = tid >> 6, lane = tid & 63;
    size_t base = (size_t)(h * NCHUNK + n);

    __shared__ __align__(16) char LB1[139776];
    unsigned short* QKb  = (unsigned short*)(LB1 + 0);        // 128*104
    unsigned short* Pb   = (unsigned short*)(LB1 + 26624);    // 64*104
    unsigned short* RHSw = (unsigned short*)(LB1 + 39936);    // 96*72
    unsigned short* RHSv = (unsigned short*)(LB1 + 53760);    // 192*72
    unsigned short* Ab   = (unsigned short*)(LB1 + 81408);    // 64*104
    unsigned short* Atb  = (unsigned short*)(LB1 + 94720);    // 64*104
    float*          Pf   = (float*)(LB1 + 121344);            // 64*68
    unsigned short* kdT  = (unsigned short*)(LB1 + 81408);    // overlay
    unsigned short* wT   = (unsigned short*)(LB1 + 95232);    // overlay
    unsigned short* uT   = (unsigned short*)(LB1 + 109056);   // overlay
    float* gr_s = (float*)(LB1 + 138752);
    float* gc_s = gr_s + 64;
    float* be_s = gc_s + 64;
    float* egc  = be_s + 64;
    __shared__ __align__(16) float cwS[384 * 4];

    for (int f = tid; f < 384; f += 256) {
        const float* src = (f < 96)  ? (cq + (size_t)(h * 96 + f) * 4)
                         : (f < 192) ? (ck + (size_t)(h * 96 + f - 96) * 4)
                                     : (cv + (size_t)(h * 192 + f - 192) * 4);
        *(float4*)&cwS[f * 4] = *(const float4*)src;
    }
    if (tid < 64) {
        gr_s[tid] = gvec[(size_t)(t0 + tid) * HVN + h];
        be_s[tid] = bvec[(size_t)(t0 + tid) * HVN + h];
    }
    __syncthreads();
    if (tid < 64) {
        float sacc = 0.f;
        for (int j = 0; j <= tid; ++j) sacc += gr_s[j];
        gc_s[tid] = sacc;
    }
    __syncthreads();
    float gl = gc_s[63];
    if (tid < 64) egc[tid] = expf(gl - gc_s[tid]);

    int r = tid >> 2, sub = tid & 3;
    int trow = t0 + r;
    // ---- k ----
    {
        int gc0 = 1536 + h * DKN + sub * 24;
        int lc0 = 96 + sub * 24;
        float kreg[24];
        float ss = 0.f;
#pragma unroll
        for (int i = 0; i < 6; ++i) {
            float4 x0 = (trow >= 3) ? *(const float4*)(Cqkv + (size_t)(trow - 3) * QKVD + gc0 + i * 4) : make_float4(0, 0, 0, 0);
            float4 x1 = (trow >= 2) ? *(const float4*)(Cqkv + (size_t)(trow - 2) * QKVD + gc0 + i * 4) : make_float4(0, 0, 0, 0);
            float4 x2 = (trow >= 1) ? *(const float4*)(Cqkv + (size_t)(trow - 1) * QKVD + gc0 + i * 4) : make_float4(0, 0, 0, 0);
            float4 x3 = *(const float4*)(Cqkv + (size_t)trow * QKVD + gc0 + i * 4);
#pragma unroll
            for (int c = 0; c < 4; ++c) {
                float4 w = *(const float4*)&cwS[(lc0 + i * 4 + c) * 4];
                float xv = ((const float*)&x0)[c] * w.x + ((const float*)&x1)[c] * w.y
                         + ((const float*)&x2)[c] * w.z + ((const float*)&x3)[c] * w.w;
                xv = siluf(xv);
                kreg[i * 4 + c] = xv;
                ss += xv * xv;
            }
        }
        ss += __shfl_xor(ss, 1, 64);
        ss += __shfl_xor(ss, 2, 64);
        float nrm = rsqrtf(ss + EPSF);
        float ebg = be_s[r] * expf(gc_s[r]);
#pragma unroll
        for (int i = 0; i < 24; ++i) {
            float kn = kreg[i] * nrm;
            QKb[r * 104 + sub * 24 + i] = f2bf(kn);
            RHSw[(sub * 24 + i) * 72 + r] = f2bf(kn * ebg);
        }
    }
    // ---- q ----
    {
        int gc0 = h * DKN + sub * 24;
        int lc0 = sub * 24;
        float qreg[24];
        float ss = 0.f;
#pragma unroll
        for (int i = 0; i < 6; ++i) {
            float4 x0 = (trow >= 3) ? *(const float4*)(Cqkv + (size_t)(trow - 3) * QKVD + gc0 + i * 4) : make_float4(0, 0, 0, 0);
            float4 x1 = (trow >= 2) ? *(const float4*)(Cqkv + (size_t)(trow - 2) * QKVD + gc0 + i * 4) : make_float4(0, 0, 0, 0);
            float4 x2 = (trow >= 1) ? *(const float4*)(Cqkv + (size_t)(trow - 1) * QKVD + gc0 + i * 4) : make_float4(0, 0, 0, 0);
            float4 x3 = *(const float4*)(Cqkv + (size_t)trow * QKVD + gc0 + i * 4);
#pragma unroll
            for (int c = 0; c < 4; ++c) {
                float4 w = *(const float4*)&cwS[(lc0 + i * 4 + c) * 4];
                float xv = ((const float*)&x0)[c] * w.x + ((const float*)&x1)[c] * w.y
                         + ((const float*)&x2)[c] * w.z + ((const float*)&x3)[c] * w.w;
                xv = siluf(xv);
                qreg[i * 4 + c] = xv;
                ss += xv * xv;
            }
        }
        ss += __shfl_xor(ss, 1, 64);
        ss += __shfl_xor(ss, 2, 64);
        float nrm = rsqrtf(ss + EPSF) * 0.10206207261596577f;
        float eg = expf(gc_s[r]);
        unsigned short* qgp = qg_bf + base * WQG_ST + r * 104 + sub * 24;
#pragma unroll
        for (int i = 0; i < 24; ++i) {
            float qn = qreg[i] * nrm;
            QKb[(64 + r) * 104 + sub * 24 + i] = f2bf(qn);
            qgp[i] = f2bf(qn * eg);
        }
    }
    // ---- v ----
    {
        int gc0 = 3072 + h * DVN + sub * 48;
        int lc0 = 192 + sub * 48;
        float ber = be_s[r];
#pragma unroll
        for (int i = 0; i < 12; ++i) {
            float4 x0 = (trow >= 3) ? *(const float4*)(Cqkv + (size_t)(trow - 3) * QKVD + gc0 + i * 4) : make_float4(0, 0, 0, 0);
            float4 x1 = (trow >= 2) ? *(const float4*)(Cqkv + (size_t)(trow - 2) * QKVD + gc0 + i * 4) : make_float4(0, 0, 0, 0);
            float4 x2 = (trow >= 1) ? *(const float4*)(Cqkv + (size_t)(trow - 1) * QKVD + gc0 + i * 4) : make_float4(0, 0, 0, 0);
            float4 x3 = *(const float4*)(Cqkv + (size_t)trow * QKVD + gc0 + i * 4);
#pragma unroll
            for (int c = 0; c < 4; ++c) {
                float4 w = *(const float4*)&cwS[(lc0 + i * 4 + c) * 4];
                float xv = ((const float*)&x0)[c] * w.x + ((const float*)&x1)[c] * w.y
                         + ((const float*)&x2)[c] * w.z + ((const float*)&x3)[c] * w.w;
                RHSv[(sub * 48 + i * 4 + c) * 72 + r] = f2bf(siluf(xv) * ber);
            }
        }
    }
    __syncthreads();

    // MFMA1: [Kn;Qn] @ Kn^T -> A (rows<64, P init to I) and attn (rows>=64)
    {
        f32x4 acc1[2][4] = {};
#pragma unroll
        for (int ks = 0; ks < 3; ++ks) {
            int ko = ks * 32 + (lane >> 4) * 8;
            short8 af[2], bfv[4];
#pragma unroll
            for (int rt2 = 0; rt2 < 2; ++rt2)
                af[rt2] = *(const short8*)&QKb[(wave * 32 + rt2 * 16 + (lane & 15)) * 104 + ko];
#pragma unroll
            for (int ct = 0; ct < 4; ++ct)
                bfv[ct] = *(const short8*)&QKb[(ct * 16 + (lane & 15)) * 104 + ko];
#pragma unroll
            for (int rt2 = 0; rt2 < 2; ++rt2)
#pragma unroll
                for (int ct = 0; ct < 4; ++ct)
                    acc1[rt2][ct] = __builtin_amdgcn_mfma_f32_16x16x32_bf16(af[rt2], bfv[ct], acc1[rt2][ct], 0, 0, 0);
        }
#pragma unroll
        for (int rt2 = 0; rt2 < 2; ++rt2)
#pragma unroll
            for (int ct = 0; ct < 4; ++ct)
#pragma unroll
                for (int j = 0; j < 4; ++j) {
                    int rr = wave * 32 + rt2 * 16 + (lane >> 4) * 4 + j;
                    int cc = ct * 16 + (lane & 15);
                    float val = acc1[rt2][ct][j];
                    if (rr < 64) {
                        float av = (rr > cc) ? -be_s[rr] * expf(gc_s[rr] - gc_s[cc]) * val : 0.f;
                        unsigned short ab = f2bf(av);
                        Ab[rr * 104 + cc] = ab;
                        Atb[cc * 104 + rr] = ab;
                        float pv = (rr == cc) ? 1.f : 0.f;   // P0 = I
                        Pf[rr * 68 + cc] = pv;
                        Pb[rr * 104 + cc] = f2bf(pv);
                    } else {
                        int ar = rr - 64;
                        float av = (ar >= cc) ? expf(gc_s[ar] - gc_s[cc]) * val : 0.f;
                        at_bf[base * AT_ST + ar * 72 + cc] = f2bf(av);
                    }
                }
    }
    __syncthreads();

    // commuted doubling: 6 levels, 2 barriers/level
#pragma unroll 1
    for (int lev = 0; lev < 6; ++lev) {
        f32x4 d[4] = {};
        f32x4 e[4];
#pragma unroll
        for (int ct = 0; ct < 4; ++ct)
#pragma unroll
            for (int j = 0; j < 4; ++j)
                e[ct][j] = Pf[(wave * 16 + (lane >> 4) * 4 + j) * 68 + ct * 16 + (lane & 15)];
#pragma unroll
        for (int ks = 0; ks < 2; ++ks) {
            int ko = ks * 32 + (lane >> 4) * 8;
            short8 aA = *(const short8*)&Ab[(wave * 16 + (lane & 15)) * 104 + ko];
            short8 aP = *(const short8*)&Pb[(wave * 16 + (lane & 15)) * 104 + ko];
#pragma unroll
            for (int ct = 0; ct < 4; ++ct) {
                short8 bAt = *(const short8*)&Atb[(ct * 16 + (lane & 15)) * 104 + ko];
                if (lev < 5) d[ct] = __builtin_amdgcn_mfma_f32_16x16x32_bf16(aA, bAt, d[ct], 0, 0, 0);
                e[ct] = __builtin_amdgcn_mfma_f32_16x16x32_bf16(aP, bAt, e[ct], 0, 0, 0);
            }
        }
        __syncthreads();
#pragma unroll
        for (int ct = 0; ct < 4; ++ct)
#pragma unroll
            for (int j = 0; j < 4; ++j) {
                int rr = wave * 16 + (lane >> 4) * 4 + j;
                int cc = ct * 16 + (lane & 15);
                if (lev < 5) {
                    unsigned short hb = f2bf(d[ct][j]);
                    Ab[rr * 104 + cc] = hb;
                    Atb[cc * 104 + rr] = hb;
                }
                float pv = e[ct][j];
                Pf[rr * 68 + cc] = pv;
                Pb[rr * 104 + cc] = f2bf(pv);
            }
        __syncthreads();
    }
    // overlay kdT/wT/uT (Ab/Atb/Pf dead)
    for (int f = tid; f < 6144; f += 256) {
        int d = f >> 6, tt = f & 63;
        kdT[d * 72 + tt] = f2bf(bf2f(QKb[tt * 104 + d]) * egc[tt]);
    }

#pragma unroll 1
    for (int i = 0; i < 18; ++i) {
        int id = wave * 18 + i;
        int rt = id & 3, ct = id >> 2;
        f32x4 o4 = {};
#pragma unroll
        for (int ks = 0; ks < 2; ++ks) {
            int ko = ks * 32 + (lane >> 4) * 8;
            short8 a0 = *(const short8*)&Pb[(rt * 16 + (lane & 15)) * 104 + ko];
            short8 b0 = (ct < 12)
                ? *(const short8*)&RHSv[(ct * 16 + (lane & 15)) * 72 + ko]
                : *(const short8*)&RHSw[((ct - 12) * 16 + (lane & 15)) * 72 + ko];
            o4 = __builtin_amdgcn_mfma_f32_16x16x32_bf16(a0, b0, o4, 0, 0, 0);
        }
#pragma unroll
        for (int j = 0; j < 4; ++j) {
            int rr = rt * 16 + (lane >> 4) * 4 + j;
            int nn = ct * 16 + (lane & 15);
            if (ct < 12) {
                u_ws[base * U_ST + rr * 192 + nn] = o4[j];
                uT[nn * 72 + rr] = f2bf(o4[j]);
            } else {
                w_bf[base * WQG_ST + rr * 104 + (nn - 192)] = f2bf(-o4[j]);
                wT[(nn - 192) * 72 + rr] = f2bf(o4[j]);
            }
        }
    }
    __syncthreads();

    // fused tprep: Tn = e^gl I - kd^T w (bf16, stride-104), Ct = u^T kd (bf16)
    float eglv = expf(gl);
#pragma unroll 1
    for (int q = 0; q < 27; ++q) {
        int id = wave * 27 + q;
        f32x4 acc = {};
        if (id < 36) {
            int jt = id / 6, kt = id % 6;
#pragma unroll
            for (int ks = 0; ks < 2; ++ks) {
                int ko = ks * 32 + (lane >> 4) * 8;
                short8 a0 = *(const short8*)&kdT[(jt * 16 + (lane & 15)) * 72 + ko];
                short8 b0 = *(const short8*)&wT[(kt * 16 + (lane & 15)) * 72 + ko];
                acc = __builtin_amdgcn_mfma_f32_16x16x32_bf16(a0, b0, acc, 0, 0, 0);
            }
#pragma unroll
            for (int rr = 0; rr < 4; ++rr) {
                int j = jt * 16 + (lane >> 4) * 4 + rr;
                int k = kt * 16 + (lane & 15);
                float val = -acc[rr];
                if (j == k) val += eglv;
                Tn[base * TN_STRIDE + j * 104 + k] = f2bf(val);
            }
        } else {
            int cid = id - 36;
            int it = cid / 6, jt = cid % 6;
#pragma unroll
            for (int ks = 0; ks < 2; ++ks) {
                int ko = ks * 32 + (lane >> 4) * 8;
                short8 a0 = *(const short8*)&uT[(it * 16 + (lane & 15)) * 72 + ko];
                short8 b0 = *(const short8*)&kdT[(jt * 16 + (lane & 15)) * 72 + ko];
                acc = __builtin_amdgcn_mfma_f32_16x16x32_bf16(a0, b0, acc, 0, 0, 0);
            }
#pragma unroll
            for (int rr = 0; rr < 4; ++rr)
                Ct[base * CT_ST + (size_t)(it * 16 + (lane >> 4) * 4 + rr) * 96 + jt * 16 + (lane & 15)] = f2bf(acc[rr]);
        }
    }
}

// ---------------- mscan ----------------
__global__ __launch_bounds__(128) void mscan(const unsigned short* __restrict__ Ct,
                                             const unsigned short* __restrict__ Tn,
                                             unsigned short* __restrict__ s_bf) {
    int rg = blockIdx.x, h = blockIdx.y;
    int tid = threadIdx.x, wave = tid >> 6, lane = tid & 63;
    __shared__ __align__(16) unsigned short St[48 * 104];
    __shared__ __align__(16) unsigned short TnB[2][TN_STRIDE];
    __shared__ __align__(16) unsigned short CtB[2][48 * 96];
    for (int i = tid; i < 48 * 104; i += 128) St[i] = 0;

    {
        const char* cp = (const char*)(Ct + (size_t)(h * NCHUNK) * CT_ST + rg * (48 * 96));
        const char* tp = (const char*)(Tn + (size_t)(h * NCHUNK) * TN_STRIDE);
        for (int q = wave; q < 9; q += 2)
            gld_lds16(cp + (size_t)q * 1024 + lane * 16, (char*)&CtB[0][0] + (size_t)q * 1024);
#pragma unroll
        for (int q = 0; q < 10; ++q) {
            size_t o = (size_t)(wave * 10 + q) * 1024 + lane * 16;
            gld_lds16(tp + o, (char*)&TnB[0][0] + (size_t)(wave * 10 + q) * 1024);
        }
    }
    f32x4 acc[3][3];
    int colw = wave * 48;
    __syncthreads();

#pragma unroll 1
    for (int n = 0; n < NCHUNK; ++n) {
        size_t base = (size_t)(h * NCHUNK + n);
        int cur = n & 1;
        if (n + 1 < NCHUNK) {
            const char* cp = (const char*)(Ct + (base + 1) * CT_ST + rg * (48 * 96));
            const char* tp = (const char*)(Tn + (base + 1) * TN_STRIDE);
            for (int q = wave; q < 9; q += 2)
                gld_lds16(cp + (size_t)q * 1024 + lane * 16, (char*)&CtB[cur ^ 1][0] + (size_t)q * 1024);
#pragma unroll
            for (int q = 0; q < 10; ++q) {
                size_t o = (size_t)(wave * 10 + q) * 1024 + lane * 16;
                gld_lds16(tp + o, (char*)&TnB[cur ^ 1][0] + (size_t)(wave * 10 + q) * 1024);
            }
        }
        {
            unsigned short* sp = s_bf + base * S_ST + rg * 4992;
            for (int f = tid; f < 624; f += 128)
                *(short8*)(sp + f * 8) = *(const short8*)&St[f * 8];
        }
#pragma unroll
        for (int it = 0; it < 3; ++it)
#pragma unroll
            for (int jt = 0; jt < 3; ++jt) {
                int irow = it * 16 + (lane >> 4) * 4;
                int col = colw + jt * 16 + (lane & 15);
#pragma unroll
                for (int r = 0; r < 4; ++r)
                    acc[it][jt][r] = bf2f(CtB[cur][(irow + r) * 96 + col]);
            }
#pragma unroll
        for (int ks = 0; ks < 3; ++ks) {
            int ko = ks * 32 + (lane >> 4) * 8;
            short8 af[3], bfv[3];
#pragma unroll
            for (int it = 0; it < 3; ++it)
                af[it] = *(const short8*)&St[(it * 16 + (lane & 15)) * 104 + ko];
#pragma unroll
            for (int jt = 0; jt < 3; ++jt)
                bfv[jt] = *(const short8*)&TnB[cur][(colw + jt * 16 + (lane & 15)) * 104 + ko];
#pragma unroll
            for (int it = 0; it < 3; ++it)
#pragma unroll
                for (int jt = 0; jt < 3; ++jt)
                    acc[it][jt] = __builtin_amdgcn_mfma_f32_16x16x32_bf16(af[it], bfv[jt], acc[it][jt], 0, 0, 0);
        }
        __syncthreads();
#pragma unroll
        for (int it = 0; it < 3; ++it)
#pragma unroll
            for (int jt = 0; jt < 3; ++jt)
#pragma unroll
                for (int r = 0; r < 4; ++r)
                    St[(it * 16 + (lane >> 4) * 4 + r) * 104 + colw + jt * 16 + (lane & 15)] = f2bf(acc[it][jt][r]);
        __syncthreads();
    }
}

// ---------------- phase2b (MFMA) + fused gate/RMSNorm -> obf ----------------
#define P2_ST 0
#define P2_W  39936
#define P2_QG 53248
#define P2_AT 66560
#define P2_U  75776
#define P2_VN 125952
__global__ __launch_bounds__(256) void phase2b_mfma(const unsigned short* __restrict__ s_bf,
                                                    const unsigned short* __restrict__ w_bf,
                                                    const unsigned short* __restrict__ qg_bf,
                                                    const unsigned short* __restrict__ at_bf,
                                                    const float* __restrict__ u_ws,
                                                    const unsigned short* __restrict__ Cgate,
                                                    const float* __restrict__ nw,
                                                    unsigned short* __restrict__ obf) {
    __shared__ __align__(16) char LB[153600];
    unsigned short* StB = (unsigned short*)(LB + P2_ST);
    unsigned short* wB  = (unsigned short*)(LB + P2_W);
    unsigned short* qgB = (unsigned short*)(LB + P2_QG);
    unsigned short* atB = (unsigned short*)(LB + P2_AT);
    float* uF           = (float*)(LB + P2_U);
    unsigned short* vnB = (unsigned short*)(LB + P2_VN);
    int n = blockIdx.x, h = blockIdx.y;
    size_t base = (size_t)(h * NCHUNK + n);
    int tid = threadIdx.x, wave = tid >> 6, lane = tid & 63;
    int i0w = wave * 48;
    {
        const char* sp = (const char*)(s_bf + base * S_ST);
        const char* wp = (const char*)(w_bf + base * WQG_ST);
        const char* qp = (const char*)(qg_bf + base * WQG_ST);
        const char* ap = (const char*)(at_bf + base * AT_ST);
        for (int q = wave; q < 39; q += 4)
            gld_lds16(sp + (size_t)q * 1024 + lane * 16, LB + P2_ST + (size_t)q * 1024);
        for (int q = wave; q < 13; q += 4)
            gld_lds16(wp + (size_t)q * 1024 + lane * 16, LB + P2_W + (size_t)q * 1024);
        for (int q = wave; q < 13; q += 4)
            gld_lds16(qp + (size_t)q * 1024 + lane * 16, LB + P2_QG + (size_t)q * 1024);
        for (int q = wave; q < 9; q += 4)
            gld_lds16(ap + (size_t)q * 1024 + lane * 16, LB + P2_AT + (size_t)q * 1024);
    }
    {
        const float* up = u_ws + base * U_ST;
        for (int f = tid; f < 3072; f += 256) {
            int t = f / 48, c4 = (f % 48) * 4;
            *(float4*)&uF[t * 196 + c4] = *(const float4*)(up + t * 192 + c4);
        }
    }
    __syncthreads();
    {
        f32x4 acc[3][4];
#pragma unroll
        for (int it = 0; it < 3; ++it)
#pragma unroll
            for (int jt = 0; jt < 4; ++jt)
#pragma unroll
                for (int r = 0; r < 4; ++r)
                    acc[it][jt][r] = uF[(jt * 16 + (lane & 15)) * 196 + i0w + it * 16 + (lane >> 4) * 4 + r];
#pragma unroll
        for (int ks = 0; ks < 3; ++ks) {
            int ko = ks * 32 + (lane >> 4) * 8;
            short8 af[3], bfv[4];
#pragma unroll
            for (int it = 0; it < 3; ++it)
                af[it] = *(const short8*)&StB[(i0w + it * 16 + (lane & 15)) * 104 + ko];
#pragma unroll
            for (int jt = 0; jt < 4; ++jt)
                bfv[jt] = *(const short8*)&wB[(jt * 16 + (lane & 15)) * 104 + ko];
#pragma unroll
            for (int it = 0; it < 3; ++it)
#pragma unroll
                for (int jt = 0; jt < 4; ++jt)
                    acc[it][jt] = __builtin_amdgcn_mfma_f32_16x16x32_bf16(af[it], bfv[jt], acc[it][jt], 0, 0, 0);
        }
#pragma unroll
        for (int it = 0; it < 3; ++it)
#pragma unroll
            for (int jt = 0; jt < 4; ++jt)
#pragma unroll
                for (int r = 0; r < 4; ++r)
                    vnB[(i0w + it * 16 + (lane >> 4) * 4 + r) * 72 + jt * 16 + (lane & 15)] = f2bf(acc[it][jt][r]);
    }
    f32x4 acc2[3][4] = {};
#pragma unroll
    for (int ks = 0; ks < 3; ++ks) {
        int ko = ks * 32 + (lane >> 4) * 8;
        short8 af[3], bfv[4];
#pragma unroll
        for (int it = 0; it < 3; ++it)
            af[it] = *(const short8*)&StB[(i0w + it * 16 + (lane & 15)) * 104 + ko];
#pragma unroll
        for (int jt = 0; jt < 4; ++jt)
            bfv[jt] = *(const short8*)&qgB[(jt * 16 + (lane & 15)) * 104 + ko];
#pragma unroll
        for (int it = 0; it < 3; ++it)
#pragma unroll
            for (int jt = 0; jt < 4; ++jt)
                acc2[it][jt] = __builtin_amdgcn_mfma_f32_16x16x32_bf16(af[it], bfv[jt], acc2[it][jt], 0, 0, 0);
    }
#pragma unroll
    for (int ks = 0; ks < 2; ++ks) {
        int ko = ks * 32 + (lane >> 4) * 8;
        short8 af[3], bfv[4];
#pragma unroll
        for (int it = 0; it < 3; ++it)
            af[it] = *(const short8*)&vnB[(i0w + it * 16 + (lane & 15)) * 72 + ko];
#pragma unroll
        for (int jt = 0; jt < 4; ++jt)
            bfv[jt] = *(const short8*)&atB[(jt * 16 + (lane & 15)) * 72 + ko];
#pragma unroll
        for (int it = 0; it < 3; ++it)
#pragma unroll
            for (int jt = 0; jt < 4; ++jt)
                acc2[it][jt] = __builtin_amdgcn_mfma_f32_16x16x32_bf16(af[it], bfv[jt], acc2[it][jt], 0, 0, 0);
    }
    __syncthreads();
    float* oF = (float*)(LB + 0);
#pragma unroll
    for (int it = 0; it < 3; ++it)
#pragma unroll
        for (int jt = 0; jt < 4; ++jt)
#pragma unroll
            for (int r = 0; r < 4; ++r)
                oF[(i0w + it * 16 + (lane >> 4) * 4 + r) * 68 + jt * 16 + (lane & 15)] = acc2[it][jt][r];
    __syncthreads();

    float* ssq = (float*)(LB + 131072);
    float* rno = (float*)(LB + 132096);
    int jj = tid >> 2, qq = tid & 3;
    int t0 = n * CHUNKN;
    {
        const unsigned short* gp = Cgate + (size_t)(t0 + jj) * VDIMN + h * DVN + qq * 48;
        float ss = 0.f;
#pragma unroll 4
        for (int m = 0; m < 48; ++m) {
            int i = qq * 48 + m;
            float x = oF[i * 68 + jj];
            float g = bf2f(gp[m]);
            float xv = x * siluf(g);
            oF[i * 68 + jj] = xv;
            ss += xv * xv;
        }
        ssq[jj * 4 + qq] = ss;
    }
    __syncthreads();
    if (tid < 64) {
        float tot = ssq[tid * 4] + ssq[tid * 4 + 1] + ssq[tid * 4 + 2] + ssq[tid * 4 + 3];
        rno[tid] = rsqrtf(tot * (1.f / 192.f) + EPSF);
    }
    __syncthreads();
    {
        float rr2 = rno[jj];
        unsigned short* op = obf + (size_t)(t0 + jj) * VDIMN + h * DVN + qq * 48;
#pragma unroll 4
        for (int m = 0; m < 48; ++m) {
            int i = qq * 48 + m;
            op[m] = f2bf(oF[i * 68 + jj] * rr2 * nw[i]);
        }
    }
}

extern "C" void kernel_launch(void* const* d_in, const int* in_sizes, int n_in,
                              void* d_out, int out_size, void* d_ws, size_t ws_size,
                              hipStream_t stream) {
    (void)in_sizes; (void)n_in; (void)out_size;
    const float* X    = (const float*)d_in[0];
    const float* Wq   = (const float*)d_in[1];
    const float* Wk   = (const float*)d_in[2];
    const float* Wv   = (const float*)d_in[3];
    const float* Wb   = (const float*)d_in[4];
    const float* Wa   = (const float*)d_in[5];
    const float* Wg   = (const float*)d_in[6];
    const float* Wo   = (const float*)d_in[7];
    const float* cq   = (const float*)d_in[8];
    const float* ck   = (const float*)d_in[9];
    const float* cv   = (const float*)d_in[10];
    const float* Alog = (const float*)d_in[11];
    const float* dtb  = (const float*)d_in[12];
    const float* nw   = (const float*)d_in[13];

    const size_t OFF_XBF   = 0;
    const size_t OFF_WALLT = 8388608;
    const size_t OFF_WOT   = 46137344;
    const size_t OFF_CQKV  = 58720256;
    const size_t OFF_CGATE = 109051904;
    const size_t OFF_CT    = 134217728;
    const size_t OFF_TN    = OFF_CT + 37748736;
    const size_t OFF_GVEC  = 184549376;
    const size_t OFF_BVEC  = 184680448;
    const size_t OFF_U     = 184819712;
    const size_t OFF_W     = 209985536;
    const size_t OFF_QG    = 222568448;
    const size_t OFF_AT    = OFF_XBF;
    const size_t OFF_S     = OFF_CQKV;
    const size_t OFF_OBF   = OFF_WALLT + 25165824;
    const size_t OFF_OPART = OFF_CQKV;
    const size_t NEEDED    = 235151360;
    if (ws_size < NEEDED) return;

    char* ws = (char*)d_ws;
    unsigned short* Xbf   = (unsigned short*)(ws + OFF_XBF);
    unsigned short* WallT = (unsigned short*)(ws + OFF_WALLT);
    unsigned short* WoT   = (unsigned short*)(ws + OFF_WOT);
    float* Cqkv  = (float*)(ws + OFF_CQKV);
    unsigned short* Cgate = (unsigned short*)(ws + OFF_CGATE);
    float* gvec  = (float*)(ws + OFF_GVEC);
    float* bvec  = (float*)(ws + OFF_BVEC);
    float* u_ws  = (float*)(ws + OFF_U);
    unsigned short* w_bf  = (unsigned short*)(ws + OFF_W);
    unsigned short* qg_bf = (unsigned short*)(ws + OFF_QG);
    unsigned short* at_bf = (unsigned short*)(ws + OFF_AT);
    unsigned short* Ct    = (unsigned short*)(ws + OFF_CT);
    unsigned short* Tn    = (unsigned short*)(ws + OFF_TN);
    unsigned short* s_bf  = (unsigned short*)(ws + OFF_S);
    unsigned short* obf   = (unsigned short*)(ws + OFF_OBF);
    float* opart = (float*)(ws + OFF_OPART);

    prep_all<<<8192, 256, 0, stream>>>(X, Wb, Wa, Alog, dtb, bvec, gvec, Xbf,
                                       Wq, Wk, Wv, Wg, Wo, WallT, WoT);

    gemm_bt2<<<dim3(9216 / 128, 2048 / 128), 256, 0, stream>>>(Xbf, WallT,
                                                               Cqkv, QKVD, QKVD / 128,
                                                               Cgate, VDIMN, 2048, 2048);

    phase1_mfma<<<dim3(NCHUNK, HVN), 256, 0, stream>>>(Cqkv, cq, ck, cv, gvec, bvec,
                                                       u_ws, w_bf, qg_bf, at_bf, Ct, Tn);
    mscan<<<dim3(4, HVN), 128, 0, stream>>>(Ct, Tn, s_bf);
    phase2b_mfma<<<dim3(NCHUNK, HVN), 256, 0, stream>>>(s_bf, w_bf, qg_bf, at_bf, u_ws,
                                                        Cgate, nw, obf);

    gemm_btk<<<dim3(2048 / 128, 2048 / 128, 3), 256, 0, stream>>>(obf, WoT, (float*)d_out, opart,
                                                                  2048, 2048, 3072);
    addk<<<4096, 256, 0, stream>>>((float*)d_out, opart, 2048 * 2048);
}